// Round 12
// baseline (971.481 us; speedup 1.0000x reference)
//
#include <hip/hip_runtime.h>
#include <math.h>

// GINE GNN: 3x [fused edge-linear + gather + relu + segment-sum] + MLP GEMMs + sigmoid head.
// R4 (champion base): CSR via rank-from-histogram + 4B perm scatter + gather-side ea permute.
// R10/R13: GEMM reg-prefetch + 32x128 tiles — both ~neutral; GEMM pool is structurally bound.
// R14 = 939.5us. Profile: aggregates dominate (3x ~138us); aggregate<64> == aggregate<128>
//     despite half the bytes => per-edge load-issue/latency bound, not channel math.
// R15: aggregate edge-group 4 -> 8. Kernel sits at 36 VGPR (compiler minimized in-flight
//     state to ~2 edges); budget to 64 VGPR is occupancy-free (waves halve at 64/128/256).
//     Hoisting 8 srcp + 8 x-gathers per group doubles memory-level parallelism per wave
//     with zero structural change (no LDS, no vmcnt asm — the R7/R9 failure modes).

#define BLK 256

typedef __attribute__((ext_vector_type(2))) float f32x2;

__device__ inline f32x2 pk_fma(f32x2 a, f32x2 b, f32x2 c) {
    f32x2 d;
    asm("v_pk_fma_f32 %0, %1, %2, %3" : "=v"(d) : "v"(a), "v"(b), "v"(c));
    return d;
}

// ---------------- CSR build ----------------

// edge_index may be int64 (reference) or int32 (JAX x64 off). int64 LE => odd words all 0.
__global__ void detect_kernel(const unsigned int* __restrict__ ei, int* __restrict__ flag) {
    int t = blockIdx.x * blockDim.x + threadIdx.x;
    if (t < 1024) {
        if (ei[2 * t + 1] != 0u) atomicOr(flag, 1);  // nonzero odd word => int32 mode
    }
}

// histogram + rank; rank within dst-bucket comes free from the atomic return.
// d < 65536 (N=50000) and rank < 65536 (max degree ~70 here) => pack d | r<<16.
__global__ void convert_hist_kernel(const int* __restrict__ ei32, const long long* __restrict__ ei64,
                                    const int* __restrict__ flag, int E,
                                    unsigned int* __restrict__ drank,
                                    int* __restrict__ counts) {
    int e = blockIdx.x * blockDim.x + threadIdx.x;
    if (e >= E) return;
    int d;
    if (*flag) d = ei32[E + e];
    else       d = (int)ei64[E + e];
    unsigned int r = (unsigned int)atomicAdd(&counts[d], 1);
    drank[e] = (unsigned int)d | (r << 16);
}

// single-block scan: 256 threads, each owns a contiguous chunk
__global__ void scan_kernel(const int* __restrict__ counts, int* __restrict__ offsets, int n) {
    __shared__ int tsum[256];
    __shared__ int texcl[256];
    int t = threadIdx.x;
    int chunk = (n + 255) >> 8;
    int b = t * chunk, e = min(b + chunk, n);
    int s = 0;
    for (int i = b; i < e; i++) s += counts[i];
    tsum[t] = s;
    __syncthreads();
    if (t == 0) {
        int run = 0;
        for (int i = 0; i < 256; i++) { texcl[i] = run; run += tsum[i]; }
        offsets[n] = run;  // == E
    }
    __syncthreads();
    int run = texcl[t];
    for (int i = b; i < e; i++) { offsets[i] = run; run += counts[i]; }
}

// scatter only the 4B permutation index (no atomic: pos = offsets[d] + rank)
__global__ void scatter_perm_kernel(const unsigned int* __restrict__ drank,
                                    const int* __restrict__ offsets,
                                    int* __restrict__ perm, int E) {
    int e = blockIdx.x * blockDim.x + threadIdx.x;
    if (e >= E) return;
    unsigned int v = drank[e];
    perm[offsets[v & 0xffffu] + (int)(v >> 16)] = e;
}

// inverted permute: thread group owns CSR position p (coalesced writes),
// gathers the ea row (random reads, L3-resident) and src directly from edge_index.
// 4 threads per edge, one float4 each.
__global__ __launch_bounds__(256) void gather_ea_kernel(
    const int* __restrict__ perm,
    const int* __restrict__ ei32, const long long* __restrict__ ei64,
    const int* __restrict__ flag,
    const float4* __restrict__ ea4,
    int* __restrict__ srcp, float4* __restrict__ eap4, int E) {
    int t = blockIdx.x * blockDim.x + threadIdx.x;
    int p = t >> 2, q = t & 3;
    if (p >= E) return;
    int e = perm[p];
    if (q == 0) {
        int s;
        if (*flag) s = ei32[e];
        else       s = (int)ei64[e];
        srcp[p] = s;
    }
    eap4[(size_t)p * 4 + q] = ea4[(size_t)e * 4 + q];
}

// ---------------- fused aggregation ----------------
// h[node] = x[node] + sum_{e: dst=node} relu( x[src_e] + ea_e @ We + be )
// One wave per node; lane owns C=D/64 channels; edge-linear via v_pk_fma_f32 over k-pairs.
// R15: 8-edge groups — 8 srcp + 8 x-gathers hoisted ahead of compute for 2x the
// outstanding loads per wave (fits the free <=64 VGPR budget).
template <int D>
__global__ __launch_bounds__(256) void aggregate_kernel(
    const float* __restrict__ x, const float* __restrict__ eap,
    const int* __restrict__ srcp,
    const float* __restrict__ We, const float* __restrict__ be,
    const int* __restrict__ offsets,
    float* __restrict__ h, int n) {
    constexpr int C = D / 64;
    int lane = threadIdx.x & 63;
    int node = __builtin_amdgcn_readfirstlane(blockIdx.x * 4 + (threadIdx.x >> 6));
    if (node >= n) return;
    int c0 = lane * C;

    // weights packed over k-pairs: wp[j][t] = {We[2t][c0+j], We[2t+1][c0+j]}
    f32x2 wp[C][8];
#pragma unroll
    for (int j = 0; j < C; j++)
#pragma unroll
        for (int t = 0; t < 8; t++) {
            f32x2 v; v.x = We[(2 * t) * D + c0 + j]; v.y = We[(2 * t + 1) * D + c0 + j];
            wp[j][t] = v;
        }
    float bias[C], acc[C];
#pragma unroll
    for (int j = 0; j < C; j++) {
        bias[j] = be[c0 + j];
        acc[j] = x[(size_t)node * D + c0 + j];
    }
    int p = offsets[node], pe = offsets[node + 1];

    // 8 edges per iteration: all 8 srcp + 8 x-gathers issued before compute
    for (; p + 8 <= pe; p += 8) {
        int sv[8];
#pragma unroll
        for (int u = 0; u < 8; u++) sv[u] = srcp[p + u];
        float xv[8][C];
#pragma unroll
        for (int u = 0; u < 8; u++) {
            const float* rr = x + (size_t)sv[u] * D + c0;
            if constexpr (C == 2) {
                float2 tv = *(const float2*)rr;
                xv[u][0] = tv.x; xv[u][1] = tv.y;
            } else {
                xv[u][0] = *rr;
            }
        }
#pragma unroll
        for (int u = 0; u < 8; u++) {
            const float4* er = (const float4*)(eap + (size_t)(p + u) * 16);
            float4 e0 = er[0], e1 = er[1], e2 = er[2], e3 = er[3];
            f32x2 ev[8];
            ev[0].x = e0.x; ev[0].y = e0.y;  ev[1].x = e0.z; ev[1].y = e0.w;
            ev[2].x = e1.x; ev[2].y = e1.y;  ev[3].x = e1.z; ev[3].y = e1.w;
            ev[4].x = e2.x; ev[4].y = e2.y;  ev[5].x = e2.z; ev[5].y = e2.w;
            ev[6].x = e3.x; ev[6].y = e3.y;  ev[7].x = e3.z; ev[7].y = e3.w;
#pragma unroll
            for (int j = 0; j < C; j++) {
                f32x2 prod; prod.x = xv[u][j] + bias[j]; prod.y = 0.f;
#pragma unroll
                for (int t = 0; t < 8; t++) prod = pk_fma(ev[t], wp[j][t], prod);
                acc[j] += fmaxf(prod.x + prod.y, 0.f);
            }
        }
    }
    // 4-edge group
    for (; p + 4 <= pe; p += 4) {
        int sv[4];
#pragma unroll
        for (int u = 0; u < 4; u++) sv[u] = srcp[p + u];
        float xv[4][C];
#pragma unroll
        for (int u = 0; u < 4; u++) {
            const float* rr = x + (size_t)sv[u] * D + c0;
            if constexpr (C == 2) {
                float2 tv = *(const float2*)rr;
                xv[u][0] = tv.x; xv[u][1] = tv.y;
            } else {
                xv[u][0] = *rr;
            }
        }
#pragma unroll
        for (int u = 0; u < 4; u++) {
            const float4* er = (const float4*)(eap + (size_t)(p + u) * 16);
            float4 e0 = er[0], e1 = er[1], e2 = er[2], e3 = er[3];
            f32x2 ev[8];
            ev[0].x = e0.x; ev[0].y = e0.y;  ev[1].x = e0.z; ev[1].y = e0.w;
            ev[2].x = e1.x; ev[2].y = e1.y;  ev[3].x = e1.z; ev[3].y = e1.w;
            ev[4].x = e2.x; ev[4].y = e2.y;  ev[5].x = e2.z; ev[5].y = e2.w;
            ev[6].x = e3.x; ev[6].y = e3.y;  ev[7].x = e3.z; ev[7].y = e3.w;
#pragma unroll
            for (int j = 0; j < C; j++) {
                f32x2 prod; prod.x = xv[u][j] + bias[j]; prod.y = 0.f;
#pragma unroll
                for (int t = 0; t < 8; t++) prod = pk_fma(ev[t], wp[j][t], prod);
                acc[j] += fmaxf(prod.x + prod.y, 0.f);
            }
        }
    }
    // tail
    for (; p < pe; p++) {
        int s = srcp[p];
        const float* xr = x + (size_t)s * D + c0;
        float xv[C];
        if constexpr (C == 2) { float2 t = *(const float2*)xr; xv[0] = t.x; xv[1] = t.y; }
        else xv[0] = *xr;
        const float4* er = (const float4*)(eap + (size_t)p * 16);
        float4 e0 = er[0], e1 = er[1], e2 = er[2], e3 = er[3];
        f32x2 ev[8];
        ev[0].x = e0.x; ev[0].y = e0.y;  ev[1].x = e0.z; ev[1].y = e0.w;
        ev[2].x = e1.x; ev[2].y = e1.y;  ev[3].x = e1.z; ev[3].y = e1.w;
        ev[4].x = e2.x; ev[4].y = e2.y;  ev[5].x = e2.z; ev[5].y = e2.w;
        ev[6].x = e3.x; ev[6].y = e3.y;  ev[7].x = e3.z; ev[7].y = e3.w;
#pragma unroll
        for (int j = 0; j < C; j++) {
            f32x2 prod; prod.x = xv[j] + bias[j]; prod.y = 0.f;
#pragma unroll
            for (int t = 0; t < 8; t++) prod = pk_fma(ev[t], wp[j][t], prod);
            acc[j] += fmaxf(prod.x + prod.y, 0.f);
        }
    }
#pragma unroll
    for (int j = 0; j < C; j++) h[(size_t)node * D + c0 + j] = acc[j];
}

// ---------------- fp32 GEMM: C[n,128] = relu(A[n,K] @ B[K,128] + bias) ----------------
// R13: 32x128 tile per block, 256 threads, 4x4 accumulators, 2-barrier + reg-prefetch loop.
template <int K>
__global__ __launch_bounds__(256) void gemm_kernel(
    const float* __restrict__ A, const float* __restrict__ B,
    const float* __restrict__ bias, float* __restrict__ C, int n) {
    __shared__ __align__(16) float As[16][36];   // transposed A tile (32 rows), padded
    __shared__ __align__(16) float Bs[16][128];
    int t = threadIdx.x;
    int row0 = blockIdx.x * 32;
    int tr = t >> 5, tc = t & 31;  // rows tr*4..+4, cols tc*4..+4
    float acc[4][4];
#pragma unroll
    for (int r = 0; r < 4; r++)
#pragma unroll
        for (int c = 0; c < 4; c++) acc[r][c] = 0.f;

    int lr = t & 31, lk = (t >> 5) * 2;  // A staging: row lr, k-offset lk (2 floats)
    int bk = t >> 4, bc = (t & 15) * 8;  // B staging

    int grow = row0 + lr;
    const float* aptr = A + (size_t)grow * K + lk;
    float2 a;
    if (grow < n) a = *(const float2*)aptr;
    else a = make_float2(0.f, 0.f);
    const float4* bp = (const float4*)(B + (size_t)bk * 128 + bc);
    float4 b0 = bp[0], b1 = bp[1];

#pragma unroll 1
    for (int ks = 0; ks < K; ks += 16) {
        As[lk + 0][lr] = a.x; As[lk + 1][lr] = a.y;
        *(float4*)&Bs[bk][bc] = b0;
        *(float4*)&Bs[bk][bc + 4] = b1;
        __syncthreads();
        if (ks + 16 < K) {  // issue next tile's loads; consumed after the FMA loop
            if (grow < n) a = *(const float2*)(aptr + ks + 16);
            const float4* bp2 = (const float4*)(B + (size_t)(ks + 16 + bk) * 128 + bc);
            b0 = bp2[0]; b1 = bp2[1];
        }
#pragma unroll
        for (int kk = 0; kk < 16; kk++) {
            float4 a0 = *(const float4*)&As[kk][tr * 4];
            float4 bv = *(const float4*)&Bs[kk][tc * 4];
            float ar[4] = {a0.x, a0.y, a0.z, a0.w};
            float bc4[4] = {bv.x, bv.y, bv.z, bv.w};
#pragma unroll
            for (int r = 0; r < 4; r++)
#pragma unroll
                for (int c = 0; c < 4; c++) acc[r][c] = fmaf(ar[r], bc4[c], acc[r][c]);
        }
        __syncthreads();
    }
    float4 bb = *(const float4*)(bias + tc * 4);
#pragma unroll
    for (int r = 0; r < 4; r++) {
        int gr = row0 + tr * 4 + r;
        if (gr < n) {
            float4 v;
            v.x = fmaxf(acc[r][0] + bb.x, 0.f);
            v.y = fmaxf(acc[r][1] + bb.y, 0.f);
            v.z = fmaxf(acc[r][2] + bb.z, 0.f);
            v.w = fmaxf(acc[r][3] + bb.w, 0.f);
            *(float4*)(C + (size_t)gr * 128 + tc * 4) = v;
        }
    }
}

// ---------------- head: out = sigmoid(x @ Wlin + blin) ----------------
__global__ __launch_bounds__(256) void final_kernel(
    const float* __restrict__ x, const float* __restrict__ Wlin,
    const float* __restrict__ blin, float* __restrict__ out, int n) {
    int lane = threadIdx.x & 63;
    int node = blockIdx.x * 4 + (threadIdx.x >> 6);
    if (node >= n) return;
    float2 w = *(const float2*)(Wlin + lane * 2);
    float2 xv = *(const float2*)(x + (size_t)node * 128 + lane * 2);
    float v = xv.x * w.x + xv.y * w.y;
#pragma unroll
    for (int off = 32; off; off >>= 1) v += __shfl_down(v, off, 64);
    if (lane == 0) out[node] = 1.f / (1.f + expf(-(v + blin[0])));
}

// ---------------- launch ----------------
extern "C" void kernel_launch(void* const* d_in, const int* in_sizes, int n_in,
                              void* d_out, int out_size, void* d_ws, size_t ws_size,
                              hipStream_t stream) {
    const float* x_in = (const float*)d_in[0];
    const void* ei    = d_in[1];
    const float* ea   = (const float*)d_in[2];
    const float* We[3]  = {(const float*)d_in[3], (const float*)d_in[9],  (const float*)d_in[15]};
    const float* be[3]  = {(const float*)d_in[4], (const float*)d_in[10], (const float*)d_in[16]};
    const float* W1[3]  = {(const float*)d_in[5], (const float*)d_in[11], (const float*)d_in[17]};
    const float* b1[3]  = {(const float*)d_in[6], (const float*)d_in[12], (const float*)d_in[18]};
    const float* W2[3]  = {(const float*)d_in[7], (const float*)d_in[13], (const float*)d_in[19]};
    const float* b2[3]  = {(const float*)d_in[8], (const float*)d_in[14], (const float*)d_in[20]};
    const float* Wlin = (const float*)d_in[21];
    const float* blin = (const float*)d_in[22];
    float* out = (float*)d_out;

    const int N = in_sizes[0] / 64;   // 50000
    const int E = in_sizes[1] / 2;    // 1.6M

    size_t off = 0;
    auto alloc = [&](size_t bytes) {
        void* p = (char*)d_ws + off;
        off += (bytes + 255) & ~(size_t)255;
        return p;
    };
    int*          flag    = (int*)alloc(4);
    unsigned int* drank   = (unsigned int*)alloc((size_t)E * 4);
    int*          counts  = (int*)alloc((size_t)N * 4);
    int*          offsets = (int*)alloc((size_t)(N + 1) * 4);
    int*          perm    = (int*)alloc((size_t)E * 4);
    int*          srcp    = (int*)alloc((size_t)E * 4);
    float*        eap     = (float*)alloc((size_t)E * 16 * 4);
    float*        bufA    = (float*)alloc((size_t)N * 128 * 4);
    float*        bufB    = (float*)alloc((size_t)N * 128 * 4);
    float*        bufC    = (float*)alloc((size_t)N * 128 * 4);

    hipMemsetAsync(flag, 0, 4, stream);
    hipMemsetAsync(counts, 0, (size_t)N * 4, stream);

    int egrid = (E + BLK - 1) / BLK;
    detect_kernel<<<4, BLK, 0, stream>>>((const unsigned int*)ei, flag);
    convert_hist_kernel<<<egrid, BLK, 0, stream>>>((const int*)ei, (const long long*)ei, flag, E,
                                                   drank, counts);
    scan_kernel<<<1, BLK, 0, stream>>>(counts, offsets, N);
    scatter_perm_kernel<<<egrid, BLK, 0, stream>>>(drank, offsets, perm, E);
    int g4grid = ((E * 4) + BLK - 1) / BLK;
    gather_ea_kernel<<<g4grid, BLK, 0, stream>>>(perm, (const int*)ei, (const long long*)ei, flag,
                                                 (const float4*)ea, srcp, (float4*)eap, E);

    int ngrid4 = (N + 3) / 4;
    int ggrid  = (N + 31) / 32;

    // layer 0: d=64
    aggregate_kernel<64><<<ngrid4, BLK, 0, stream>>>(x_in, eap, srcp, We[0], be[0], offsets, bufA, N);
    gemm_kernel<64><<<ggrid, BLK, 0, stream>>>(bufA, W1[0], b1[0], bufB, N);
    gemm_kernel<128><<<ggrid, BLK, 0, stream>>>(bufB, W2[0], b2[0], bufC, N);
    // layer 1: d=128
    aggregate_kernel<128><<<ngrid4, BLK, 0, stream>>>(bufC, eap, srcp, We[1], be[1], offsets, bufA, N);
    gemm_kernel<128><<<ggrid, BLK, 0, stream>>>(bufA, W1[1], b1[1], bufB, N);
    gemm_kernel<128><<<ggrid, BLK, 0, stream>>>(bufB, W2[1], b2[1], bufC, N);
    // layer 2: d=128
    aggregate_kernel<128><<<ngrid4, BLK, 0, stream>>>(bufC, eap, srcp, We[2], be[2], offsets, bufA, N);
    gemm_kernel<128><<<ggrid, BLK, 0, stream>>>(bufA, W1[2], b1[2], bufB, N);
    gemm_kernel<128><<<ggrid, BLK, 0, stream>>>(bufB, W2[2], b2[2], bufC, N);

    final_kernel<<<ngrid4, BLK, 0, stream>>>(bufC, Wlin, blin, out, N);
}

// Round 13
// 925.851 us; speedup vs baseline: 1.0493x; 1.0493x over previous
//
#include <hip/hip_runtime.h>
#include <math.h>

// GINE GNN: 3x [fused edge-linear + gather + relu + segment-sum] + MLP GEMMs + sigmoid head.
// R4/R14 champion (939.5us): CSR via rank-from-histogram + 4B perm scatter + gather-side ea
//     permute; k-pair pk_fma aggregate; 32x128 2-barrier reg-prefetch GEMM.
// Failed aggregate attacks: R5 channel-pack (neutral), R7 LDS pipeline (occ collapse),
//     R9 readfirstlane-of-values (vmcnt drains), R15 8-edge groups (occ 63->55%).
// R16: scalar-path eap for LAYER 0 ONLY (aggregate64s). aggregate<64> == aggregate<128> in
//     time despite half the work => VMEM-issue bound; 4 of 5 loads/edge are the wave-uniform
//     eap row. s_load_dwordx16 fetches it once per wave on the SMEM pipe (lgkmcnt), and
//     v_pk_fma_f32 takes the SGPR pair directly (1 SGPR src is legal) — 5 VMEM/edge -> 1.
//     Layers 1-2 + GEMMs are bit-identical champion code.

#define BLK 256

typedef __attribute__((ext_vector_type(2))) float f32x2;
typedef __attribute__((ext_vector_type(16))) float f32x16;

__device__ inline f32x2 pk_fma(f32x2 a, f32x2 b, f32x2 c) {
    f32x2 d;
    asm("v_pk_fma_f32 %0, %1, %2, %3" : "=v"(d) : "v"(a), "v"(b), "v"(c));
    return d;
}
// a comes from an SGPR pair (VOP3P allows one scalar source)
__device__ inline f32x2 pk_fma_s(f32x2 a, f32x2 b, f32x2 c) {
    f32x2 d;
    asm("v_pk_fma_f32 %0, %1, %2, %3" : "=v"(d) : "s"(a), "v"(b), "v"(c));
    return d;
}
// wave-uniform 64B row -> 16 SGPRs via the scalar-memory pipe
__device__ inline f32x16 sload16(const float* p) {
    f32x16 r;
    asm volatile("s_load_dwordx16 %0, %1, 0x0" : "=s"(r) : "s"(p));
    return r;
}

// ---------------- CSR build ----------------

// edge_index may be int64 (reference) or int32 (JAX x64 off). int64 LE => odd words all 0.
__global__ void detect_kernel(const unsigned int* __restrict__ ei, int* __restrict__ flag) {
    int t = blockIdx.x * blockDim.x + threadIdx.x;
    if (t < 1024) {
        if (ei[2 * t + 1] != 0u) atomicOr(flag, 1);  // nonzero odd word => int32 mode
    }
}

// histogram + rank; rank within dst-bucket comes free from the atomic return.
// d < 65536 (N=50000) and rank < 65536 (max degree ~70 here) => pack d | r<<16.
__global__ void convert_hist_kernel(const int* __restrict__ ei32, const long long* __restrict__ ei64,
                                    const int* __restrict__ flag, int E,
                                    unsigned int* __restrict__ drank,
                                    int* __restrict__ counts) {
    int e = blockIdx.x * blockDim.x + threadIdx.x;
    if (e >= E) return;
    int d;
    if (*flag) d = ei32[E + e];
    else       d = (int)ei64[E + e];
    unsigned int r = (unsigned int)atomicAdd(&counts[d], 1);
    drank[e] = (unsigned int)d | (r << 16);
}

// single-block scan: 256 threads, each owns a contiguous chunk
__global__ void scan_kernel(const int* __restrict__ counts, int* __restrict__ offsets, int n) {
    __shared__ int tsum[256];
    __shared__ int texcl[256];
    int t = threadIdx.x;
    int chunk = (n + 255) >> 8;
    int b = t * chunk, e = min(b + chunk, n);
    int s = 0;
    for (int i = b; i < e; i++) s += counts[i];
    tsum[t] = s;
    __syncthreads();
    if (t == 0) {
        int run = 0;
        for (int i = 0; i < 256; i++) { texcl[i] = run; run += tsum[i]; }
        offsets[n] = run;  // == E
    }
    __syncthreads();
    int run = texcl[t];
    for (int i = b; i < e; i++) { offsets[i] = run; run += counts[i]; }
}

// scatter only the 4B permutation index (no atomic: pos = offsets[d] + rank)
__global__ void scatter_perm_kernel(const unsigned int* __restrict__ drank,
                                    const int* __restrict__ offsets,
                                    int* __restrict__ perm, int E) {
    int e = blockIdx.x * blockDim.x + threadIdx.x;
    if (e >= E) return;
    unsigned int v = drank[e];
    perm[offsets[v & 0xffffu] + (int)(v >> 16)] = e;
}

// inverted permute: thread group owns CSR position p (coalesced writes),
// gathers the ea row (random reads, L3-resident) and src directly from edge_index.
// 4 threads per edge, one float4 each.
__global__ __launch_bounds__(256) void gather_ea_kernel(
    const int* __restrict__ perm,
    const int* __restrict__ ei32, const long long* __restrict__ ei64,
    const int* __restrict__ flag,
    const float4* __restrict__ ea4,
    int* __restrict__ srcp, float4* __restrict__ eap4, int E) {
    int t = blockIdx.x * blockDim.x + threadIdx.x;
    int p = t >> 2, q = t & 3;
    if (p >= E) return;
    int e = perm[p];
    if (q == 0) {
        int s;
        if (*flag) s = ei32[e];
        else       s = (int)ei64[e];
        srcp[p] = s;
    }
    eap4[(size_t)p * 4 + q] = ea4[(size_t)e * 4 + q];
}

// ---------------- fused aggregation ----------------
// h[node] = x[node] + sum_{e: dst=node} relu( x[src_e] + ea_e @ We + be )

// D=64, scalar-eap variant (layer 0): eap row via s_load_dwordx16 (SMEM pipe),
// pk_fma consumes SGPR pairs directly. x-gather stays on VMEM.
__global__ __launch_bounds__(256) void aggregate64s_kernel(
    const float* __restrict__ x, const float* __restrict__ eap,
    const int* __restrict__ srcp,
    const float* __restrict__ We, const float* __restrict__ be,
    const int* __restrict__ offsets,
    float* __restrict__ h, int n) {
    constexpr int D = 64;
    int lane = threadIdx.x & 63;
    int node = __builtin_amdgcn_readfirstlane(blockIdx.x * 4 + (threadIdx.x >> 6));
    if (node >= n) return;
    int c0 = lane;

    // wp[t] = {We[2t][c0], We[2t+1][c0]}
    f32x2 wp[8];
#pragma unroll
    for (int t = 0; t < 8; t++) {
        f32x2 v; v.x = We[(2 * t) * D + c0]; v.y = We[(2 * t + 1) * D + c0];
        wp[t] = v;
    }
    float bias = be[c0];
    float acc  = x[(size_t)node * D + c0];
    // p/pe uniform in SGPRs (one-time readfirstlane per node — NOT per edge group)
    int p  = __builtin_amdgcn_readfirstlane(offsets[node]);
    int pe = __builtin_amdgcn_readfirstlane(offsets[node + 1]);

    for (; p + 4 <= pe; p += 4) {
        // 4 wave-uniform 64B eap rows on the scalar pipe (64 SGPRs in flight)
        f32x16 r0 = sload16(eap + (size_t)p * 16);
        f32x16 r1 = sload16(eap + (size_t)(p + 1) * 16);
        f32x16 r2 = sload16(eap + (size_t)(p + 2) * 16);
        f32x16 r3 = sload16(eap + (size_t)(p + 3) * 16);
        // per-lane srcp + x gathers (VMEM)
        int s0 = srcp[p], s1 = srcp[p + 1], s2 = srcp[p + 2], s3 = srcp[p + 3];
        float xv0 = x[(size_t)s0 * D + c0];
        float xv1 = x[(size_t)s1 * D + c0];
        float xv2 = x[(size_t)s2 * D + c0];
        float xv3 = x[(size_t)s3 * D + c0];
        // dep-carrying wait: consumers of r0..r3 must follow this
        asm volatile("s_waitcnt lgkmcnt(0)" : "+s"(r0), "+s"(r1), "+s"(r2), "+s"(r3));
#define EDGE_S(RU, XV)                                          \
        {                                                       \
            f32x2 prod; prod.x = (XV) + bias; prod.y = 0.f;     \
            _Pragma("unroll")                                   \
            for (int t = 0; t < 8; t++) {                       \
                f32x2 e; e.x = RU[2 * t]; e.y = RU[2 * t + 1];  \
                prod = pk_fma_s(e, wp[t], prod);                \
            }                                                   \
            acc += fmaxf(prod.x + prod.y, 0.f);                 \
        }
        EDGE_S(r0, xv0)
        EDGE_S(r1, xv1)
        EDGE_S(r2, xv2)
        EDGE_S(r3, xv3)
#undef EDGE_S
    }
    // tail: champion per-lane vector path
    for (; p < pe; p++) {
        int s = srcp[p];
        float xv0 = x[(size_t)s * D + c0];
        const float4* er = (const float4*)(eap + (size_t)p * 16);
        float4 e0 = er[0], e1 = er[1], e2 = er[2], e3 = er[3];
        f32x2 ev[8];
        ev[0].x = e0.x; ev[0].y = e0.y;  ev[1].x = e0.z; ev[1].y = e0.w;
        ev[2].x = e1.x; ev[2].y = e1.y;  ev[3].x = e1.z; ev[3].y = e1.w;
        ev[4].x = e2.x; ev[4].y = e2.y;  ev[5].x = e2.z; ev[5].y = e2.w;
        ev[6].x = e3.x; ev[6].y = e3.y;  ev[7].x = e3.z; ev[7].y = e3.w;
        f32x2 prod; prod.x = xv0 + bias; prod.y = 0.f;
#pragma unroll
        for (int t = 0; t < 8; t++) prod = pk_fma(ev[t], wp[t], prod);
        acc += fmaxf(prod.x + prod.y, 0.f);
    }
    h[(size_t)node * D + c0] = acc;
}

// D=128 (layers 1-2): R4/R14 champion version, untouched.
template <int D>
__global__ __launch_bounds__(256) void aggregate_kernel(
    const float* __restrict__ x, const float* __restrict__ eap,
    const int* __restrict__ srcp,
    const float* __restrict__ We, const float* __restrict__ be,
    const int* __restrict__ offsets,
    float* __restrict__ h, int n) {
    constexpr int C = D / 64;
    int lane = threadIdx.x & 63;
    int node = __builtin_amdgcn_readfirstlane(blockIdx.x * 4 + (threadIdx.x >> 6));
    if (node >= n) return;
    int c0 = lane * C;

    f32x2 wp[C][8];
#pragma unroll
    for (int j = 0; j < C; j++)
#pragma unroll
        for (int t = 0; t < 8; t++) {
            f32x2 v; v.x = We[(2 * t) * D + c0 + j]; v.y = We[(2 * t + 1) * D + c0 + j];
            wp[j][t] = v;
        }
    float bias[C], acc[C];
#pragma unroll
    for (int j = 0; j < C; j++) {
        bias[j] = be[c0 + j];
        acc[j] = x[(size_t)node * D + c0 + j];
    }
    int p = offsets[node], pe = offsets[node + 1];

    for (; p + 4 <= pe; p += 4) {
        int s0 = srcp[p], s1 = srcp[p + 1], s2 = srcp[p + 2], s3 = srcp[p + 3];
        float xv[4][C];
        {
            const float* r0 = x + (size_t)s0 * D + c0;
            const float* r1 = x + (size_t)s1 * D + c0;
            const float* r2 = x + (size_t)s2 * D + c0;
            const float* r3 = x + (size_t)s3 * D + c0;
            if constexpr (C == 2) {
                float2 t0 = *(const float2*)r0, t1 = *(const float2*)r1;
                float2 t2 = *(const float2*)r2, t3 = *(const float2*)r3;
                xv[0][0] = t0.x; xv[0][1] = t0.y; xv[1][0] = t1.x; xv[1][1] = t1.y;
                xv[2][0] = t2.x; xv[2][1] = t2.y; xv[3][0] = t3.x; xv[3][1] = t3.y;
            } else {
                xv[0][0] = *r0; xv[1][0] = *r1; xv[2][0] = *r2; xv[3][0] = *r3;
            }
        }
#pragma unroll
        for (int u = 0; u < 4; u++) {
            const float4* er = (const float4*)(eap + (size_t)(p + u) * 16);
            float4 e0 = er[0], e1 = er[1], e2 = er[2], e3 = er[3];
            f32x2 ev[8];
            ev[0].x = e0.x; ev[0].y = e0.y;  ev[1].x = e0.z; ev[1].y = e0.w;
            ev[2].x = e1.x; ev[2].y = e1.y;  ev[3].x = e1.z; ev[3].y = e1.w;
            ev[4].x = e2.x; ev[4].y = e2.y;  ev[5].x = e2.z; ev[5].y = e2.w;
            ev[6].x = e3.x; ev[6].y = e3.y;  ev[7].x = e3.z; ev[7].y = e3.w;
#pragma unroll
            for (int j = 0; j < C; j++) {
                f32x2 prod; prod.x = xv[u][j] + bias[j]; prod.y = 0.f;
#pragma unroll
                for (int t = 0; t < 8; t++) prod = pk_fma(ev[t], wp[j][t], prod);
                acc[j] += fmaxf(prod.x + prod.y, 0.f);
            }
        }
    }
    for (; p < pe; p++) {
        int s = srcp[p];
        const float* xr = x + (size_t)s * D + c0;
        float xv[C];
        if constexpr (C == 2) { float2 t = *(const float2*)xr; xv[0] = t.x; xv[1] = t.y; }
        else xv[0] = *xr;
        const float4* er = (const float4*)(eap + (size_t)p * 16);
        float4 e0 = er[0], e1 = er[1], e2 = er[2], e3 = er[3];
        f32x2 ev[8];
        ev[0].x = e0.x; ev[0].y = e0.y;  ev[1].x = e0.z; ev[1].y = e0.w;
        ev[2].x = e1.x; ev[2].y = e1.y;  ev[3].x = e1.z; ev[3].y = e1.w;
        ev[4].x = e2.x; ev[4].y = e2.y;  ev[5].x = e2.z; ev[5].y = e2.w;
        ev[6].x = e3.x; ev[6].y = e3.y;  ev[7].x = e3.z; ev[7].y = e3.w;
#pragma unroll
        for (int j = 0; j < C; j++) {
            f32x2 prod; prod.x = xv[j] + bias[j]; prod.y = 0.f;
#pragma unroll
            for (int t = 0; t < 8; t++) prod = pk_fma(ev[t], wp[j][t], prod);
            acc[j] += fmaxf(prod.x + prod.y, 0.f);
        }
    }
#pragma unroll
    for (int j = 0; j < C; j++) h[(size_t)node * D + c0 + j] = acc[j];
}

// ---------------- fp32 GEMM: C[n,128] = relu(A[n,K] @ B[K,128] + bias) ----------------
// R13 champion: 32x128 tile, 256 threads, 4x4 acc, 2-barrier + reg-prefetch loop.
template <int K>
__global__ __launch_bounds__(256) void gemm_kernel(
    const float* __restrict__ A, const float* __restrict__ B,
    const float* __restrict__ bias, float* __restrict__ C, int n) {
    __shared__ __align__(16) float As[16][36];   // transposed A tile (32 rows), padded
    __shared__ __align__(16) float Bs[16][128];
    int t = threadIdx.x;
    int row0 = blockIdx.x * 32;
    int tr = t >> 5, tc = t & 31;  // rows tr*4..+4, cols tc*4..+4
    float acc[4][4];
#pragma unroll
    for (int r = 0; r < 4; r++)
#pragma unroll
        for (int c = 0; c < 4; c++) acc[r][c] = 0.f;

    int lr = t & 31, lk = (t >> 5) * 2;  // A staging: row lr, k-offset lk (2 floats)
    int bk = t >> 4, bc = (t & 15) * 8;  // B staging

    int grow = row0 + lr;
    const float* aptr = A + (size_t)grow * K + lk;
    float2 a;
    if (grow < n) a = *(const float2*)aptr;
    else a = make_float2(0.f, 0.f);
    const float4* bp = (const float4*)(B + (size_t)bk * 128 + bc);
    float4 b0 = bp[0], b1 = bp[1];

#pragma unroll 1
    for (int ks = 0; ks < K; ks += 16) {
        As[lk + 0][lr] = a.x; As[lk + 1][lr] = a.y;
        *(float4*)&Bs[bk][bc] = b0;
        *(float4*)&Bs[bk][bc + 4] = b1;
        __syncthreads();
        if (ks + 16 < K) {  // issue next tile's loads; consumed after the FMA loop
            if (grow < n) a = *(const float2*)(aptr + ks + 16);
            const float4* bp2 = (const float4*)(B + (size_t)(ks + 16 + bk) * 128 + bc);
            b0 = bp2[0]; b1 = bp2[1];
        }
#pragma unroll
        for (int kk = 0; kk < 16; kk++) {
            float4 a0 = *(const float4*)&As[kk][tr * 4];
            float4 bv = *(const float4*)&Bs[kk][tc * 4];
            float ar[4] = {a0.x, a0.y, a0.z, a0.w};
            float bc4[4] = {bv.x, bv.y, bv.z, bv.w};
#pragma unroll
            for (int r = 0; r < 4; r++)
#pragma unroll
                for (int c = 0; c < 4; c++) acc[r][c] = fmaf(ar[r], bc4[c], acc[r][c]);
        }
        __syncthreads();
    }
    float4 bb = *(const float4*)(bias + tc * 4);
#pragma unroll
    for (int r = 0; r < 4; r++) {
        int gr = row0 + tr * 4 + r;
        if (gr < n) {
            float4 v;
            v.x = fmaxf(acc[r][0] + bb.x, 0.f);
            v.y = fmaxf(acc[r][1] + bb.y, 0.f);
            v.z = fmaxf(acc[r][2] + bb.z, 0.f);
            v.w = fmaxf(acc[r][3] + bb.w, 0.f);
            *(float4*)(C + (size_t)gr * 128 + tc * 4) = v;
        }
    }
}

// ---------------- head: out = sigmoid(x @ Wlin + blin) ----------------
__global__ __launch_bounds__(256) void final_kernel(
    const float* __restrict__ x, const float* __restrict__ Wlin,
    const float* __restrict__ blin, float* __restrict__ out, int n) {
    int lane = threadIdx.x & 63;
    int node = blockIdx.x * 4 + (threadIdx.x >> 6);
    if (node >= n) return;
    float2 w = *(const float2*)(Wlin + lane * 2);
    float2 xv = *(const float2*)(x + (size_t)node * 128 + lane * 2);
    float v = xv.x * w.x + xv.y * w.y;
#pragma unroll
    for (int off = 32; off; off >>= 1) v += __shfl_down(v, off, 64);
    if (lane == 0) out[node] = 1.f / (1.f + expf(-(v + blin[0])));
}

// ---------------- launch ----------------
extern "C" void kernel_launch(void* const* d_in, const int* in_sizes, int n_in,
                              void* d_out, int out_size, void* d_ws, size_t ws_size,
                              hipStream_t stream) {
    const float* x_in = (const float*)d_in[0];
    const void* ei    = d_in[1];
    const float* ea   = (const float*)d_in[2];
    const float* We[3]  = {(const float*)d_in[3], (const float*)d_in[9],  (const float*)d_in[15]};
    const float* be[3]  = {(const float*)d_in[4], (const float*)d_in[10], (const float*)d_in[16]};
    const float* W1[3]  = {(const float*)d_in[5], (const float*)d_in[11], (const float*)d_in[17]};
    const float* b1[3]  = {(const float*)d_in[6], (const float*)d_in[12], (const float*)d_in[18]};
    const float* W2[3]  = {(const float*)d_in[7], (const float*)d_in[13], (const float*)d_in[19]};
    const float* b2[3]  = {(const float*)d_in[8], (const float*)d_in[14], (const float*)d_in[20]};
    const float* Wlin = (const float*)d_in[21];
    const float* blin = (const float*)d_in[22];
    float* out = (float*)d_out;

    const int N = in_sizes[0] / 64;   // 50000
    const int E = in_sizes[1] / 2;    // 1.6M

    size_t off = 0;
    auto alloc = [&](size_t bytes) {
        void* p = (char*)d_ws + off;
        off += (bytes + 255) & ~(size_t)255;
        return p;
    };
    int*          flag    = (int*)alloc(4);
    unsigned int* drank   = (unsigned int*)alloc((size_t)E * 4);
    int*          counts  = (int*)alloc((size_t)N * 4);
    int*          offsets = (int*)alloc((size_t)(N + 1) * 4);
    int*          perm    = (int*)alloc((size_t)E * 4);
    int*          srcp    = (int*)alloc((size_t)E * 4);
    float*        eap     = (float*)alloc((size_t)E * 16 * 4);
    float*        bufA    = (float*)alloc((size_t)N * 128 * 4);
    float*        bufB    = (float*)alloc((size_t)N * 128 * 4);
    float*        bufC    = (float*)alloc((size_t)N * 128 * 4);

    hipMemsetAsync(flag, 0, 4, stream);
    hipMemsetAsync(counts, 0, (size_t)N * 4, stream);

    int egrid = (E + BLK - 1) / BLK;
    detect_kernel<<<4, BLK, 0, stream>>>((const unsigned int*)ei, flag);
    convert_hist_kernel<<<egrid, BLK, 0, stream>>>((const int*)ei, (const long long*)ei, flag, E,
                                                   drank, counts);
    scan_kernel<<<1, BLK, 0, stream>>>(counts, offsets, N);
    scatter_perm_kernel<<<egrid, BLK, 0, stream>>>(drank, offsets, perm, E);
    int g4grid = ((E * 4) + BLK - 1) / BLK;
    gather_ea_kernel<<<g4grid, BLK, 0, stream>>>(perm, (const int*)ei, (const long long*)ei, flag,
                                                 (const float4*)ea, srcp, (float4*)eap, E);

    int ngrid4 = (N + 3) / 4;
    int ggrid  = (N + 31) / 32;

    // layer 0: d=64 (scalar-eap variant)
    aggregate64s_kernel<<<ngrid4, BLK, 0, stream>>>(x_in, eap, srcp, We[0], be[0], offsets, bufA, N);
    gemm_kernel<64><<<ggrid, BLK, 0, stream>>>(bufA, W1[0], b1[0], bufB, N);
    gemm_kernel<128><<<ggrid, BLK, 0, stream>>>(bufB, W2[0], b2[0], bufC, N);
    // layer 1: d=128
    aggregate_kernel<128><<<ngrid4, BLK, 0, stream>>>(bufC, eap, srcp, We[1], be[1], offsets, bufA, N);
    gemm_kernel<128><<<ggrid, BLK, 0, stream>>>(bufA, W1[1], b1[1], bufB, N);
    gemm_kernel<128><<<ggrid, BLK, 0, stream>>>(bufB, W2[1], b2[1], bufC, N);
    // layer 2: d=128
    aggregate_kernel<128><<<ngrid4, BLK, 0, stream>>>(bufC, eap, srcp, We[2], be[2], offsets, bufA, N);
    gemm_kernel<128><<<ggrid, BLK, 0, stream>>>(bufA, W1[2], b1[2], bufB, N);
    gemm_kernel<128><<<ggrid, BLK, 0, stream>>>(bufB, W2[2], b2[2], bufC, N);

    final_kernel<<<ngrid4, BLK, 0, stream>>>(bufC, Wlin, blin, out, N);
}